// Round 2
// baseline (1113.206 us; speedup 1.0000x reference)
//
#include <hip/hip_runtime.h>
#include <hip/hip_bf16.h>

#define B_  2
#define S_  2048
#define H_  1024
#define NH_ 16
#define HD_ 64

typedef __bf16 bf16_t;
typedef __attribute__((ext_vector_type(8))) __bf16 bf16x8;
typedef __attribute__((ext_vector_type(4))) __bf16 bf16x4;
typedef __attribute__((ext_vector_type(4))) float f32x4;

__device__ __forceinline__ void glds16(const bf16_t* g, bf16_t* s) {
    __builtin_amdgcn_global_load_lds(
        (const __attribute__((address_space(1))) void*)g,
        (__attribute__((address_space(3))) void*)s, 16, 0, 0);
}

// ---------------------------------------------------------------------------
// Kernel 0: cast fp32 -> bf16. hs (4M) -> Xb, Wq/Wk/Wv (1M each) -> Wb[3].
// One float4 load + one packed 8B store per thread.
// ---------------------------------------------------------------------------
__global__ __launch_bounds__(256) void cast_bf16(
    const float* __restrict__ hs,
    const float* __restrict__ Wq, const float* __restrict__ Wk,
    const float* __restrict__ Wv,
    bf16_t* __restrict__ Xb, bf16_t* __restrict__ Wb)
{
    int i4 = blockIdx.x * 256 + threadIdx.x;      // 0 .. 1835007
    const float* src;
    bf16_t* dst;
    int off;
    if (i4 < 1048576) {
        src = hs; dst = Xb; off = i4;
    } else {
        int j = i4 - 1048576;
        int which = j >> 18;                      // 262144 chunks per W
        src = which == 0 ? Wq : (which == 1 ? Wk : Wv);
        dst = Wb + (size_t)which * 1048576;
        off = j & 262143;
    }
    float4 v = ((const float4*)src)[off];
    bf16x4 o;
    o[0] = (bf16_t)v.x; o[1] = (bf16_t)v.y; o[2] = (bf16_t)v.z; o[3] = (bf16_t)v.w;
    ((bf16x4*)dst)[off] = o;
}

// ---------------------------------------------------------------------------
// Kernel 1: m97-style bf16 GEMM, C = X * W^T + b. 128x128 tile, BK=64,
// global_load_lds width=16 staging, ds_read_b128 frags, 4 waves 2x2,
// acc[4][4] per wave. which = blockIdx.z selects q/k/v.
// q scaled by 0.125; v stored transposed [b][h][d][s].
// ---------------------------------------------------------------------------
__global__ __launch_bounds__(256) void qkv_gemm2(
    const bf16_t* __restrict__ Xb, const bf16_t* __restrict__ Wb,
    const float* __restrict__ bq, const float* __restrict__ bk,
    const float* __restrict__ bv,
    bf16_t* __restrict__ qbuf, bf16_t* __restrict__ kbuf, bf16_t* __restrict__ vT)
{
    const int which = blockIdx.z;
    const bf16_t* Wp  = Wb + (size_t)which * 1048576;
    const float* bias = which == 0 ? bq : (which == 1 ? bk : bv);

    const int m0 = blockIdx.x * 128;   // rows (b*S+s), [0,4096)
    const int n0 = blockIdx.y * 128;   // output features, [0,1024)
    const int t    = threadIdx.x;
    const int lane = t & 63;
    const int w    = t >> 6;
    const int wm   = w & 1, wn = w >> 1;
    const int lo   = lane & 15;
    const int g    = lane >> 4;

    __shared__ bf16_t As[128 * 64];
    __shared__ bf16_t Bs[128 * 64];

    f32x4 acc[4][4];
#pragma unroll
    for (int i = 0; i < 4; ++i)
#pragma unroll
        for (int j = 0; j < 4; ++j) acc[i][j] = (f32x4){0.f, 0.f, 0.f, 0.f};

    for (int kc = 0; kc < 16; ++kc) {
        // stage A and B tiles: 128 rows x 64 cols bf16 = 1024 x 16B each
#pragma unroll
        for (int i = 0; i < 4; ++i) {
            int idx = i * 256 + t;             // 0..1023
            int row = idx >> 3, seg = idx & 7;
            bf16_t* ldsbase = &As[(size_t)(i * 256 + w * 64) * 8];
            glds16(&Xb[(size_t)(m0 + row) * H_ + kc * 64 + seg * 8], ldsbase);
        }
#pragma unroll
        for (int i = 0; i < 4; ++i) {
            int idx = i * 256 + t;
            int row = idx >> 3, seg = idx & 7;
            bf16_t* ldsbase = &Bs[(size_t)(i * 256 + w * 64) * 8];
            glds16(&Wp[(size_t)(n0 + row) * H_ + kc * 64 + seg * 8], ldsbase);
        }
        __syncthreads();   // drains vmcnt (global_load_lds) + barrier

#pragma unroll
        for (int kk = 0; kk < 64; kk += 32) {
            bf16x8 af[4], bf[4];
#pragma unroll
            for (int mi = 0; mi < 4; ++mi)
                af[mi] = *(const bf16x8*)&As[(size_t)(wm * 64 + mi * 16 + lo) * 64 + kk + g * 8];
#pragma unroll
            for (int ni = 0; ni < 4; ++ni)
                bf[ni] = *(const bf16x8*)&Bs[(size_t)(wn * 64 + ni * 16 + lo) * 64 + kk + g * 8];
#pragma unroll
            for (int mi = 0; mi < 4; ++mi)
#pragma unroll
                for (int ni = 0; ni < 4; ++ni)
                    acc[mi][ni] = __builtin_amdgcn_mfma_f32_16x16x32_bf16(
                        af[mi], bf[ni], acc[mi][ni], 0, 0, 0);
        }
        __syncthreads();
    }

    const float scale = which == 0 ? 0.125f : 1.0f;
    if (which < 2) {
        bf16_t* out = which == 0 ? qbuf : kbuf;
#pragma unroll
        for (int ni = 0; ni < 4; ++ni) {
            int n = n0 + wn * 64 + ni * 16 + lo;
            int hh = n >> 6, d = n & 63;
            float bvv = bias[n];
#pragma unroll
            for (int mi = 0; mi < 4; ++mi) {
#pragma unroll
                for (int r = 0; r < 4; ++r) {
                    int m = m0 + wm * 64 + mi * 16 + g * 4 + r;
                    int bb = m >> 11, s = m & 2047;
                    float val = (acc[mi][ni][r] + bvv) * scale;
                    out[(((size_t)(bb * NH_ + hh) * S_) + s) * HD_ + d] = (bf16_t)val;
                }
            }
        }
    } else {
        // V: store transposed [b][h][d][s], packed 4 bf16 (r-consecutive s)
#pragma unroll
        for (int ni = 0; ni < 4; ++ni) {
            int n = n0 + wn * 64 + ni * 16 + lo;
            int hh = n >> 6, d = n & 63;
            float bvv = bias[n];
#pragma unroll
            for (int mi = 0; mi < 4; ++mi) {
                int m = m0 + wm * 64 + mi * 16 + g * 4;
                int bb = m >> 11, s = m & 2047;
                bf16x4 pk;
#pragma unroll
                for (int r = 0; r < 4; ++r) pk[r] = (bf16_t)(acc[mi][ni][r] + bvv);
                *(bf16x4*)&vT[(((size_t)(bb * NH_ + hh) * HD_) + d) * S_ + s] = pk;
            }
        }
    }
}

// ---------------------------------------------------------------------------
// Kernel 2: barrier-free flash attention. One block per (b, h, 64-row q tile),
// 4 waves x 16 q-rows. Q/K/V^T fragments loaded directly from global (16B
// per-lane). Only LDS use: per-wave P round-trip (C-layout -> A-layout),
// pad 88 -> 16B-aligned ds_read_b128, <=2-way bank aliasing.
// ---------------------------------------------------------------------------
__global__ __launch_bounds__(256) void attn(
    const bf16_t* __restrict__ qbuf, const bf16_t* __restrict__ kbuf,
    const bf16_t* __restrict__ vT,
    const float* __restrict__ mask, const float* __restrict__ rel,
    float* __restrict__ out)
{
    const int b = blockIdx.z, h = blockIdx.y, q0 = blockIdx.x * 64;
    const int t    = threadIdx.x;
    const int lane = t & 63;
    const int w    = t >> 6;
    const int lo   = lane & 15;
    const int g    = lane >> 4;

    __shared__ bf16_t Ps[4][16 * 88];    // per-wave, no barriers needed

    const bf16_t* qg  = qbuf + ((size_t)(b * NH_ + h) * S_ + q0) * HD_;
    const bf16_t* kg  = kbuf + (size_t)(b * NH_ + h) * S_ * HD_;
    const bf16_t* vtg = vT   + (size_t)(b * NH_ + h) * HD_ * S_;   // [d][s]
    const float*  relg  = rel + ((size_t)((b * NH_ + h) * S_ + q0)) * S_;
    const float*  maskg = mask + b * S_;

    // Q A-frags (held in registers for whole kernel), q pre-scaled by 1/8
    bf16x8 aq0 = *(const bf16x8*)&qg[(size_t)(w * 16 + lo) * HD_ + g * 8];
    bf16x8 aq1 = *(const bf16x8*)&qg[(size_t)(w * 16 + lo) * HD_ + g * 8 + 32];

    float mi[4], li[4];
    f32x4 accO[4];
#pragma unroll
    for (int r = 0; r < 4; ++r) { mi[r] = -1e30f; li[r] = 0.f; }
#pragma unroll
    for (int dt = 0; dt < 4; ++dt) accO[dt] = (f32x4){0.f, 0.f, 0.f, 0.f};

    for (int kc = 0; kc < 32; ++kc) {
        const bf16_t* kchunk = kg + (size_t)kc * 64 * HD_;

        // QK^T: 16x64 strip per wave, K frags direct from global
        f32x4 sc[4];
#pragma unroll
        for (int nt = 0; nt < 4; ++nt) {
            bf16x8 b0 = *(const bf16x8*)&kchunk[(size_t)(nt * 16 + lo) * HD_ + g * 8];
            bf16x8 b1 = *(const bf16x8*)&kchunk[(size_t)(nt * 16 + lo) * HD_ + g * 8 + 32];
            f32x4 z = (f32x4){0.f, 0.f, 0.f, 0.f};
            z = __builtin_amdgcn_mfma_f32_16x16x32_bf16(aq0, b0, z, 0, 0, 0);
            z = __builtin_amdgcn_mfma_f32_16x16x32_bf16(aq1, b1, z, 0, 0, 0);
            sc[nt] = z;
        }

        // + mask + rel_pos (fp32)
        float sv[4][4];
#pragma unroll
        for (int nt = 0; nt < 4; ++nt) {
            float mk = maskg[kc * 64 + nt * 16 + lo];
#pragma unroll
            for (int r = 0; r < 4; ++r) {
                int row = w * 16 + g * 4 + r;
                sv[r][nt] = sc[nt][r] + mk +
                            relg[(size_t)row * S_ + kc * 64 + nt * 16 + lo];
            }
        }

        // online softmax per row; write P (bf16, C-layout) to per-wave LDS
#pragma unroll
        for (int r = 0; r < 4; ++r) {
            float vmax = fmaxf(fmaxf(sv[r][0], sv[r][1]), fmaxf(sv[r][2], sv[r][3]));
#pragma unroll
            for (int mk = 1; mk < 16; mk <<= 1)
                vmax = fmaxf(vmax, __shfl_xor(vmax, mk, 16));
            float mnew  = fmaxf(mi[r], vmax);
            float alpha = __expf(mi[r] - mnew);
            float rsum = 0.f;
#pragma unroll
            for (int nt = 0; nt < 4; ++nt) {
                float p = __expf(sv[r][nt] - mnew);
                sv[r][nt] = p;
                rsum += p;
            }
#pragma unroll
            for (int mk = 1; mk < 16; mk <<= 1)
                rsum += __shfl_xor(rsum, mk, 16);
            li[r] = li[r] * alpha + rsum;
            mi[r] = mnew;
#pragma unroll
            for (int dt = 0; dt < 4; ++dt) accO[dt][r] *= alpha;
#pragma unroll
            for (int nt = 0; nt < 4; ++nt)
                Ps[w][(g * 4 + r) * 88 + nt * 16 + lo] = (bf16_t)sv[r][nt];
        }
        __builtin_amdgcn_wave_barrier();   // order P writes before reads (free)

        // PV: P(16x64) * V^T chunk, V frags direct from global
        bf16x8 pa0 = *(const bf16x8*)&Ps[w][lo * 88 + g * 8];
        bf16x8 pa1 = *(const bf16x8*)&Ps[w][lo * 88 + g * 8 + 32];
#pragma unroll
        for (int dt = 0; dt < 4; ++dt) {
            bf16x8 v0 = *(const bf16x8*)&vtg[(size_t)(dt * 16 + lo) * S_ + kc * 64 + g * 8];
            bf16x8 v1 = *(const bf16x8*)&vtg[(size_t)(dt * 16 + lo) * S_ + kc * 64 + g * 8 + 32];
            accO[dt] = __builtin_amdgcn_mfma_f32_16x16x32_bf16(pa0, v0, accO[dt], 0, 0, 0);
            accO[dt] = __builtin_amdgcn_mfma_f32_16x16x32_bf16(pa1, v1, accO[dt], 0, 0, 0);
        }
    }

    // epilogue: out[b][s][h*64+d] = O / l
#pragma unroll
    for (int dt = 0; dt < 4; ++dt) {
        int d = dt * 16 + lo;
#pragma unroll
        for (int r = 0; r < 4; ++r) {
            int row = q0 + w * 16 + g * 4 + r;
            out[((size_t)(b * S_ + row)) * H_ + h * HD_ + d] = accO[dt][r] / li[r];
        }
    }
}

extern "C" void kernel_launch(void* const* d_in, const int* in_sizes, int n_in,
                              void* d_out, int out_size, void* d_ws, size_t ws_size,
                              hipStream_t stream) {
    const float* hs   = (const float*)d_in[0];
    const float* mask = (const float*)d_in[1];
    const float* rel  = (const float*)d_in[2];
    const float* Wq   = (const float*)d_in[3];
    const float* bq   = (const float*)d_in[4];
    const float* Wk   = (const float*)d_in[5];
    const float* bk   = (const float*)d_in[6];
    const float* Wv   = (const float*)d_in[7];
    const float* bv   = (const float*)d_in[8];
    float* out = (float*)d_out;

    const size_t qkv_elems = (size_t)B_ * NH_ * S_ * HD_;  // 4,194,304
    bf16_t* qbuf = (bf16_t*)d_ws;
    bf16_t* kbuf = qbuf + qkv_elems;
    bf16_t* vT   = kbuf + qkv_elems;            // [b][h][d][s]
    bf16_t* Xb   = vT + qkv_elems;              // 4M bf16
    bf16_t* Wb   = Xb + qkv_elems;              // 3 x 1M bf16

    cast_bf16<<<dim3(7168), 256, 0, stream>>>(hs, Wq, Wk, Wv, Xb, Wb);
    qkv_gemm2<<<dim3(32, 8, 3), 256, 0, stream>>>(Xb, Wb, bq, bk, bv,
                                                  qbuf, kbuf, vT);
    attn<<<dim3(S_ / 64, NH_, B_), 256, 0, stream>>>(qbuf, kbuf, vT, mask, rel, out);
}